// Round 13
// baseline (481.336 us; speedup 1.0000x reference)
//
#include <hip/hip_runtime.h>
#include <math.h>

#define ZDIM 128
#define HDIM 100
#define NPW  (112 * 128)      // elements per padded w1/w2 plane
#define W3N  (16 * 128)       // elements per padded w3 plane
#define LDSW 132              // LDS row stride (f32) for h-tiles (proven R9/R10)
#define MSTR 12               // LDS row stride (f32) for the M bounce

typedef __attribute__((ext_vector_type(8))) short bf16x8;   // 8 bf16 in 4 VGPRs
typedef __attribute__((ext_vector_type(4))) float f32x4;

// ---------- bf16 split helpers (round-to-nearest-even) ----------
__device__ __host__ __forceinline__ unsigned short bf16_rne(float f) {
    unsigned u = __float_as_uint(f);
    unsigned r = u + 0x7FFFu + ((u >> 16) & 1u);
    return (unsigned short)(r >> 16);
}
__device__ __host__ __forceinline__ float bf16_back(unsigned short h) {
    return __uint_as_float(((unsigned)h) << 16);
}

// Fast tanh: tanh(v) = (e-1)/(e+1), e = exp(2v). err ~3e-7 abs.
__device__ __forceinline__ float fast_tanh(float v) {
    float e = __expf(2.0f * v);
    return (e - 1.0f) / (e + 1.0f);
}

// fp64 polar (Higham scaled Newton, 8 iters) — proven R4-R10.
__device__ __forceinline__ void polar3x3(const float mr[9], double X[9]) {
    #pragma unroll
    for (int r = 0; r < 9; ++r) X[r] = (double)mr[r];
    #pragma unroll 1
    for (int it = 0; it < 8; ++it) {
        double C00 = X[4]*X[8] - X[5]*X[7];
        double C01 = X[5]*X[6] - X[3]*X[8];
        double C02 = X[3]*X[7] - X[4]*X[6];
        double C10 = X[2]*X[7] - X[1]*X[8];
        double C11 = X[0]*X[8] - X[2]*X[6];
        double C12 = X[1]*X[6] - X[0]*X[7];
        double C20 = X[1]*X[5] - X[2]*X[4];
        double C21 = X[2]*X[3] - X[0]*X[5];
        double C22 = X[0]*X[4] - X[1]*X[3];
        double det = X[0]*C00 + X[1]*C01 + X[2]*C02;
        double adet = fabs(det);
        adet = adet < 1e-300 ? 1e-300 : adet;
        double sdet = (det < 0.0) ? -adet : adet;
        double nf2 = X[0]*X[0]+X[1]*X[1]+X[2]*X[2]+X[3]*X[3]+X[4]*X[4]
                   + X[5]*X[5]+X[6]*X[6]+X[7]*X[7]+X[8]*X[8];
        double nc2 = C00*C00+C01*C01+C02*C02+C10*C10+C11*C11
                   + C12*C12+C20*C20+C21*C21+C22*C22;
        double g = sqrt(sqrt(nc2 / nf2) / adet);
        double a = 0.5 * g;
        double b = 0.5 / (g * sdet);
        double Y0 = a*X[0] + b*C00, Y1 = a*X[1] + b*C01, Y2 = a*X[2] + b*C02;
        double Y3 = a*X[3] + b*C10, Y4 = a*X[4] + b*C11, Y5 = a*X[5] + b*C12;
        double Y6 = a*X[6] + b*C20, Y7 = a*X[7] + b*C21, Y8 = a*X[8] + b*C22;
        X[0]=Y0; X[1]=Y1; X[2]=Y2; X[3]=Y3; X[4]=Y4; X[5]=Y5; X[6]=Y6; X[7]=Y7; X[8]=Y8;
    }
}

// ---------- Prep: bf16x3 planes for w1, w2, w3; padded fp32 biases ----------
// R11/R12 bisect: bf16x2 (dM~1e-5) flips det for samples with sigma3 < 1e-5
// (a handful among 262k) -> absmax 1.37. bf16x3 (dM~1e-8) is the precision
// floor for batch polar/SVD: need dM << min sigma3 ~ sigma_typ/N ~ 1e-6.
__global__ void prep_split(const float* __restrict__ w1, const float* __restrict__ w2,
                           const float* __restrict__ w3, const float* __restrict__ b1,
                           const float* __restrict__ b2, const float* __restrict__ b3,
                           unsigned short* __restrict__ w1p, unsigned short* __restrict__ w2p,
                           unsigned short* __restrict__ w3b,
                           float* __restrict__ b1p, float* __restrict__ b2p,
                           float* __restrict__ b3p) {
    int idx = blockIdx.x * blockDim.x + threadIdx.x;
    if (idx < NPW) {
        int col = idx >> 7;          // 0..111
        int k   = idx & 127;         // 0..127
        float w = (col < HDIM) ? w1[(size_t)col * ZDIM + k] : 0.0f;
        unsigned short e1 = bf16_rne(w);  float r1 = w - bf16_back(e1);
        unsigned short e2 = bf16_rne(r1); float r2 = r1 - bf16_back(e2);
        unsigned short e3 = bf16_rne(r2);
        w1p[0*NPW + idx] = e1; w1p[1*NPW + idx] = e2; w1p[2*NPW + idx] = e3;

        float v = (col < HDIM && k < HDIM) ? w2[(size_t)col * HDIM + k] : 0.0f;
        unsigned short f1 = bf16_rne(v);  float s1 = v - bf16_back(f1);
        unsigned short f2 = bf16_rne(s1); float s2 = s1 - bf16_back(f2);
        unsigned short f3 = bf16_rne(s2);
        w2p[0*NPW + idx] = f1; w2p[1*NPW + idx] = f2; w2p[2*NPW + idx] = f3;
    }
    if (idx < W3N) {
        int col = idx >> 7;          // 0..15 (w3 output row r)
        int k   = idx & 127;         // 0..127 (h2 index i)
        float v = (col < 9 && k < HDIM) ? w3[(size_t)col * HDIM + k] : 0.0f;
        unsigned short f1 = bf16_rne(v);  float s1 = v - bf16_back(f1);
        unsigned short f2 = bf16_rne(s1); float s2 = s1 - bf16_back(f2);
        unsigned short f3 = bf16_rne(s2);
        w3b[0*W3N + idx] = f1; w3b[1*W3N + idx] = f2; w3b[2*W3N + idx] = f3;
    }
    if (idx < 112) {
        b1p[idx] = (idx < HDIM) ? b1[idx] : 0.0f;
        b2p[idx] = (idx < HDIM) ? b2[idx] : 0.0f;
    }
    if (idx < 16) b3p[idx] = (idx < 9) ? b3[idx] : 0.0f;
}

// ---------- Main: 3 MFMA layers (bf16x3, n-outer, packed-A) + fp64 polar ----------
// R12 chassis (n-outer: <=2 live accumulators; A packed once per tile;
// pad cols zeroed once) with R10's proven bf16x3 numerics (6 MFMA terms:
// A1B1, A1B2, A2B1, A1B3, A2B2, A3B1; residual ~2^-24).
// Layouts (proven R9/R10): A/B (lane&15, lane>>4, elem); C/D col=lane&15,
// row=4*(lane>>4)+reg.
__global__ __launch_bounds__(256) void pose_mfma(
    const float* __restrict__ x,
    const unsigned short* __restrict__ w1p,
    const unsigned short* __restrict__ w2p,
    const unsigned short* __restrict__ w3b,
    const float* __restrict__ b1p,
    const float* __restrict__ b2p,
    const float* __restrict__ b3p,
    float* __restrict__ out)
{
    __shared__ float hbuf_all[4][16 * LDSW + 16 * MSTR];   // 36864 B -> 4 blocks/CU
    const int lane = threadIdx.x & 63;
    const int wid  = threadIdx.x >> 6;
    float* hb = hbuf_all[wid];
    float* mb = hb + 16 * LDSW;

    const long long base = ((long long)blockIdx.x * 4 + wid) * 64;
    const int lrow = lane & 15;      // A-row / B-col / C-col slot
    const int lgrp = lane >> 4;      // k-group / C row-group

    float myM[9] = {0,0,0,0,0,0,0,0,0};

    // Zero logical pad cols 112..127 ONCE (h1/h2 writes only touch cols 0..111).
    #pragma unroll
    for (int q = 0; q < 4; ++q) {
        int row = lgrp * 4 + q;
        int col = 112 + lrow;
        hb[row * LDSW + (col ^ ((row & 3) << 3))] = 0.0f;
    }

    #pragma unroll 1
    for (int t = 0; t < 4; ++t) {
        const float* xrow = x + (size_t)(base + t * 16 + lrow) * ZDIM;

        // ---- pack x A-fragments ONCE (bf16x3): 48 VGPRs, reused by all 7 n ----
        bf16x8 xA1[4], xA2[4], xA3[4];
        #pragma unroll
        for (int kt = 0; kt < 4; ++kt) {
            const int k0 = kt * 32 + lgrp * 8;
            const float4 xa = *reinterpret_cast<const float4*>(xrow + k0);
            const float4 xb = *reinterpret_cast<const float4*>(xrow + k0 + 4);
            const float xr[8] = { xa.x, xa.y, xa.z, xa.w, xb.x, xb.y, xb.z, xb.w };
            #pragma unroll
            for (int e = 0; e < 8; ++e) {
                unsigned short e1 = bf16_rne(xr[e]); float r1 = xr[e] - bf16_back(e1);
                unsigned short e2 = bf16_rne(r1);    float r2 = r1    - bf16_back(e2);
                xA1[kt][e] = (short)e1;
                xA2[kt][e] = (short)e2;
                xA3[kt][e] = (short)bf16_rne(r2);
            }
        }

        // ================= Layer 1: n-outer, 1 accumulator =================
        #pragma unroll 2
        for (int n = 0; n < 7; ++n) {
            f32x4 C = (f32x4){0.f, 0.f, 0.f, 0.f};
            #pragma unroll
            for (int kt = 0; kt < 4; ++kt) {
                const unsigned short* bp = w1p + ((size_t)(n * 16 + lrow) * 128 + kt * 32 + lgrp * 8);
                bf16x8 B1 = *reinterpret_cast<const bf16x8*>(bp);
                bf16x8 B2 = *reinterpret_cast<const bf16x8*>(bp + NPW);
                bf16x8 B3 = *reinterpret_cast<const bf16x8*>(bp + 2 * NPW);
                C = __builtin_amdgcn_mfma_f32_16x16x32_bf16(xA1[kt], B1, C, 0, 0, 0);
                C = __builtin_amdgcn_mfma_f32_16x16x32_bf16(xA1[kt], B2, C, 0, 0, 0);
                C = __builtin_amdgcn_mfma_f32_16x16x32_bf16(xA2[kt], B1, C, 0, 0, 0);
                C = __builtin_amdgcn_mfma_f32_16x16x32_bf16(xA1[kt], B3, C, 0, 0, 0);
                C = __builtin_amdgcn_mfma_f32_16x16x32_bf16(xA2[kt], B2, C, 0, 0, 0);
                C = __builtin_amdgcn_mfma_f32_16x16x32_bf16(xA3[kt], B1, C, 0, 0, 0);
            }
            const float bv = b1p[n * 16 + lrow];
            #pragma unroll
            for (int q = 0; q < 4; ++q) {
                int row = lgrp * 4 + q;
                int col = n * 16 + lrow;
                hb[row * LDSW + (col ^ ((row & 3) << 3))] = fmaxf(C[q] + bv, 0.0f);
            }
        }

        // ---- pack h1 A-fragments ONCE ----
        bf16x8 hA1[4], hA2[4], hA3[4];
        #pragma unroll
        for (int kt = 0; kt < 4; ++kt) {
            const int col0 = kt * 32 + lgrp * 8;
            const int sc = col0 ^ ((lrow & 3) << 3);
            const float4 ha = *reinterpret_cast<const float4*>(hb + lrow * LDSW + sc);
            const float4 hc = *reinterpret_cast<const float4*>(hb + lrow * LDSW + sc + 4);
            const float hr[8] = { ha.x, ha.y, ha.z, ha.w, hc.x, hc.y, hc.z, hc.w };
            #pragma unroll
            for (int e = 0; e < 8; ++e) {
                unsigned short e1 = bf16_rne(hr[e]); float r1 = hr[e] - bf16_back(e1);
                unsigned short e2 = bf16_rne(r1);    float r2 = r1    - bf16_back(e2);
                hA1[kt][e] = (short)e1;
                hA2[kt][e] = (short)e2;
                hA3[kt][e] = (short)bf16_rne(r2);
            }
        }

        // ================= Layer 2: n-outer (h2 overwrites h1 in LDS; h1 in regs) ====
        #pragma unroll 2
        for (int n = 0; n < 7; ++n) {
            f32x4 C = (f32x4){0.f, 0.f, 0.f, 0.f};
            #pragma unroll
            for (int kt = 0; kt < 4; ++kt) {
                const unsigned short* bp = w2p + ((size_t)(n * 16 + lrow) * 128 + kt * 32 + lgrp * 8);
                bf16x8 B1 = *reinterpret_cast<const bf16x8*>(bp);
                bf16x8 B2 = *reinterpret_cast<const bf16x8*>(bp + NPW);
                bf16x8 B3 = *reinterpret_cast<const bf16x8*>(bp + 2 * NPW);
                C = __builtin_amdgcn_mfma_f32_16x16x32_bf16(hA1[kt], B1, C, 0, 0, 0);
                C = __builtin_amdgcn_mfma_f32_16x16x32_bf16(hA1[kt], B2, C, 0, 0, 0);
                C = __builtin_amdgcn_mfma_f32_16x16x32_bf16(hA2[kt], B1, C, 0, 0, 0);
                C = __builtin_amdgcn_mfma_f32_16x16x32_bf16(hA1[kt], B3, C, 0, 0, 0);
                C = __builtin_amdgcn_mfma_f32_16x16x32_bf16(hA2[kt], B2, C, 0, 0, 0);
                C = __builtin_amdgcn_mfma_f32_16x16x32_bf16(hA3[kt], B1, C, 0, 0, 0);
            }
            const float bv = b2p[n * 16 + lrow];
            #pragma unroll
            for (int q = 0; q < 4; ++q) {
                int row = lgrp * 4 + q;
                int col = n * 16 + lrow;
                hb[row * LDSW + (col ^ ((row & 3) << 3))] = fast_tanh(C[q] + bv);
            }
        }

        // ---- pack h2 A-fragments (reuse hA regs; pads still zero) ----
        #pragma unroll
        for (int kt = 0; kt < 4; ++kt) {
            const int col0 = kt * 32 + lgrp * 8;
            const int sc = col0 ^ ((lrow & 3) << 3);
            const float4 ha = *reinterpret_cast<const float4*>(hb + lrow * LDSW + sc);
            const float4 hc = *reinterpret_cast<const float4*>(hb + lrow * LDSW + sc + 4);
            const float hr[8] = { ha.x, ha.y, ha.z, ha.w, hc.x, hc.y, hc.z, hc.w };
            #pragma unroll
            for (int e = 0; e < 8; ++e) {
                unsigned short e1 = bf16_rne(hr[e]); float r1 = hr[e] - bf16_back(e1);
                unsigned short e2 = bf16_rne(r1);    float r2 = r1    - bf16_back(e2);
                hA1[kt][e] = (short)e1;
                hA2[kt][e] = (short)e2;
                hA3[kt][e] = (short)bf16_rne(r2);
            }
        }

        // ================= Layer 3: one 16-col tile =================
        f32x4 C3 = (f32x4){0.f, 0.f, 0.f, 0.f};
        #pragma unroll
        for (int kt = 0; kt < 4; ++kt) {
            const unsigned short* bp = w3b + ((size_t)lrow * 128 + kt * 32 + lgrp * 8);
            bf16x8 B1 = *reinterpret_cast<const bf16x8*>(bp);
            bf16x8 B2 = *reinterpret_cast<const bf16x8*>(bp + W3N);
            bf16x8 B3 = *reinterpret_cast<const bf16x8*>(bp + 2 * W3N);
            C3 = __builtin_amdgcn_mfma_f32_16x16x32_bf16(hA1[kt], B1, C3, 0, 0, 0);
            C3 = __builtin_amdgcn_mfma_f32_16x16x32_bf16(hA1[kt], B2, C3, 0, 0, 0);
            C3 = __builtin_amdgcn_mfma_f32_16x16x32_bf16(hA2[kt], B1, C3, 0, 0, 0);
            C3 = __builtin_amdgcn_mfma_f32_16x16x32_bf16(hA1[kt], B3, C3, 0, 0, 0);
            C3 = __builtin_amdgcn_mfma_f32_16x16x32_bf16(hA2[kt], B2, C3, 0, 0, 0);
            C3 = __builtin_amdgcn_mfma_f32_16x16x32_bf16(hA3[kt], B1, C3, 0, 0, 0);
        }

        // M + b3 -> LDS bounce (proven R10)
        {
            float bv3 = b3p[lrow];
            if (lrow < 9) {
                #pragma unroll
                for (int q = 0; q < 4; ++q)
                    mb[(lgrp * 4 + q) * MSTR + lrow] = C3[q] + bv3;
            }
        }
        if (((lane >> 2) & 3) == t) {
            int row = 4 * (lane >> 4) + (lane & 3);
            const float4 m0 = *reinterpret_cast<const float4*>(mb + row * MSTR);
            const float4 m1 = *reinterpret_cast<const float4*>(mb + row * MSTR + 4);
            const float4 m2 = *reinterpret_cast<const float4*>(mb + row * MSTR + 8);
            myM[0] = m0.x; myM[1] = m0.y; myM[2] = m0.z; myM[3] = m0.w;
            myM[4] = m1.x; myM[5] = m1.y; myM[6] = m1.z; myM[7] = m1.w;
            myM[8] = m2.x;
        }
    }

    // ---------- Polar (fp64, proven) on this lane's sample ----------
    double X[9];
    polar3x3(myM, X);

    const long long samp = base + 16 * ((lane >> 2) & 3) + 4 * (lane >> 4) + (lane & 3);
    float* o = out + samp * 9;
    #pragma unroll
    for (int r = 0; r < 9; ++r) o[r] = (float)X[r];
}

// ---------- Fallback: R6-style 1 thread/sample VALU kernel ----------
__global__ __launch_bounds__(256) void pose_simple(
    const float* __restrict__ x,
    const float* __restrict__ w1, const float* __restrict__ b1,
    const float* __restrict__ w2, const float* __restrict__ b2,
    const float* __restrict__ w3, const float* __restrict__ b3,
    float* __restrict__ out, int nB)
{
    int tid = blockIdx.x * blockDim.x + threadIdx.x;
    if (tid >= nB) return;
    const float* xrow = x + (size_t)tid * ZDIM;

    float h1[HDIM];
    #pragma unroll
    for (int j = 0; j < HDIM; ++j) h1[j] = b1[j];
    #pragma unroll 1
    for (int k = 0; k < ZDIM; ++k) {
        float xv = xrow[k];
        #pragma unroll
        for (int j = 0; j < HDIM; ++j)
            h1[j] = fmaf(xv, w1[(size_t)j * ZDIM + k], h1[j]);
    }
    #pragma unroll
    for (int j = 0; j < HDIM; ++j) h1[j] = fmaxf(h1[j], 0.0f);

    float mr[9];
    #pragma unroll
    for (int r = 0; r < 9; ++r) mr[r] = b3[r];
    #pragma unroll 1
    for (int i = 0; i < HDIM; ++i) {
        const float* w2row = w2 + (size_t)i * HDIM;
        float a0 = 0.f, a1 = 0.f, a2 = 0.f, a3 = 0.f;
        #pragma unroll
        for (int j = 0; j < HDIM; j += 4) {
            a0 = fmaf(w2row[j + 0], h1[j + 0], a0);
            a1 = fmaf(w2row[j + 1], h1[j + 1], a1);
            a2 = fmaf(w2row[j + 2], h1[j + 2], a2);
            a3 = fmaf(w2row[j + 3], h1[j + 3], a3);
        }
        float tv = fast_tanh((a0 + a1) + (a2 + a3) + b2[i]);
        #pragma unroll
        for (int r = 0; r < 9; ++r)
            mr[r] = fmaf(w3[(size_t)r * HDIM + i], tv, mr[r]);
    }

    double X[9];
    polar3x3(mr, X);
    float* o = out + (size_t)tid * 9;
    #pragma unroll
    for (int r = 0; r < 9; ++r) o[r] = (float)X[r];
}

extern "C" void kernel_launch(void* const* d_in, const int* in_sizes, int n_in,
                              void* d_out, int out_size, void* d_ws, size_t ws_size,
                              hipStream_t stream) {
    const float* x  = (const float*)d_in[0];
    const float* w1 = (const float*)d_in[1];
    const float* b1 = (const float*)d_in[2];
    const float* w2 = (const float*)d_in[3];
    const float* b2 = (const float*)d_in[4];
    const float* w3 = (const float*)d_in[5];
    const float* b3 = (const float*)d_in[6];
    float* out = (float*)d_out;

    int nB = in_sizes[0] / ZDIM;

    // ws layout (bytes), bf16x3 planes
    const size_t off_w2p = (size_t)3 * NPW * sizeof(unsigned short);             // 86016
    const size_t off_w3b = off_w2p * 2;                                          // 172032
    const size_t off_b1p = off_w3b + (size_t)3 * W3N * sizeof(unsigned short);   // +12288
    const size_t off_b2p = off_b1p + 112 * sizeof(float);
    const size_t off_b3p = off_b2p + 112 * sizeof(float);
    const size_t need    = off_b3p + 16 * sizeof(float);

    if (ws_size >= need && (nB % 256) == 0) {
        unsigned short* w1p = (unsigned short*)d_ws;
        unsigned short* w2p = (unsigned short*)((char*)d_ws + off_w2p);
        unsigned short* w3b = (unsigned short*)((char*)d_ws + off_w3b);
        float* b1p = (float*)((char*)d_ws + off_b1p);
        float* b2p = (float*)((char*)d_ws + off_b2p);
        float* b3p = (float*)((char*)d_ws + off_b3p);

        prep_split<<<(NPW + 255) / 256, 256, 0, stream>>>(w1, w2, w3, b1, b2, b3,
                                                          w1p, w2p, w3b, b1p, b2p, b3p);
        dim3 grid(nB / 256);   // 1024 blocks; 4 waves/block; 64 samples/wave
        pose_mfma<<<grid, 256, 0, stream>>>(x, w1p, w2p, w3b, b1p, b2p, b3p, out);
    } else {
        dim3 grid((nB + 255) / 256);
        pose_simple<<<grid, 256, 0, stream>>>(x, w1, b1, w2, b2, w3, b3, out, nB);
    }
}